// Round 7
// baseline (10045.436 us; speedup 1.0000x reference)
//
#include <hip/hip_runtime.h>
#include <cstdint>
#include <cstddef>

#define SEQ   2048
#define BATCH 64
#define HID   512

// ---------------------------------------------------------------------------
// proj GEMM: C[m][n] = sum_k A[m][k] * W[n][k] + bias[n]
// A: [M][512] row-major, W: [512][512] row-major (NT layout -> both row reads)
// BM=128 BN=128 BK=16, 256 threads, per-thread 8 rows x (4+4) cols
// ---------------------------------------------------------------------------
__global__ __launch_bounds__(256)
void proj_gemm(const float* __restrict__ A, const float* __restrict__ W,
               const float* __restrict__ bias, float* __restrict__ C)
{
    __shared__ float As[16][132];   // transposed: As[k][row], pad 132
    __shared__ float Bs[16][132];   // Bs[k][col]
    const int t  = threadIdx.x;
    const int bm = blockIdx.x >> 2;     // 1024 m-tiles
    const int bn = blockIdx.x & 3;      // 4 n-tiles
    const int m0 = bm * 128;
    const int n0 = bn * 128;
    const int tn = t & 15;
    const int tm = t >> 4;

    float acc[8][8];
#pragma unroll
    for (int i = 0; i < 8; ++i)
#pragma unroll
        for (int j = 0; j < 8; ++j) acc[i][j] = 0.f;

    const int lrow = t >> 2;   // 0..63
    const int lk4  = t & 3;    // float4 index within 16-wide k tile

    for (int kk = 0; kk < 512; kk += 16) {
#pragma unroll
        for (int i = 0; i < 2; ++i) {
            const int row = lrow + i * 64;
            float4 va = *(const float4*)&A[(size_t)(m0 + row) * 512 + kk + lk4 * 4];
            As[lk4 * 4 + 0][row] = va.x;
            As[lk4 * 4 + 1][row] = va.y;
            As[lk4 * 4 + 2][row] = va.z;
            As[lk4 * 4 + 3][row] = va.w;
            float4 vb = *(const float4*)&W[(size_t)(n0 + row) * 512 + kk + lk4 * 4];
            Bs[lk4 * 4 + 0][row] = vb.x;
            Bs[lk4 * 4 + 1][row] = vb.y;
            Bs[lk4 * 4 + 2][row] = vb.z;
            Bs[lk4 * 4 + 3][row] = vb.w;
        }
        __syncthreads();
#pragma unroll
        for (int k = 0; k < 16; ++k) {
            float4 a0 = *(const float4*)&As[k][tm * 8];
            float4 a1 = *(const float4*)&As[k][tm * 8 + 4];
            float4 b0 = *(const float4*)&Bs[k][tn * 4];
            float4 b1 = *(const float4*)&Bs[k][64 + tn * 4];
            float ar[8] = {a0.x, a0.y, a0.z, a0.w, a1.x, a1.y, a1.z, a1.w};
            float bc[8] = {b0.x, b0.y, b0.z, b0.w, b1.x, b1.y, b1.z, b1.w};
#pragma unroll
            for (int i = 0; i < 8; ++i)
#pragma unroll
                for (int j = 0; j < 8; ++j)
                    acc[i][j] = fmaf(ar[i], bc[j], acc[i][j]);
        }
        __syncthreads();
    }

    float4 bv0 = *(const float4*)&bias[n0 + tn * 4];
    float4 bv1 = *(const float4*)&bias[n0 + 64 + tn * 4];
    const float bb[8] = {bv0.x, bv0.y, bv0.z, bv0.w, bv1.x, bv1.y, bv1.z, bv1.w};
#pragma unroll
    for (int i = 0; i < 8; ++i) {
        const size_t rowoff = (size_t)(m0 + tm * 8 + i) * 512 + n0;
        float4 o0, o1;
        o0.x = acc[i][0] + bb[0]; o0.y = acc[i][1] + bb[1];
        o0.z = acc[i][2] + bb[2]; o0.w = acc[i][3] + bb[3];
        o1.x = acc[i][4] + bb[4]; o1.y = acc[i][5] + bb[5];
        o1.z = acc[i][6] + bb[6]; o1.w = acc[i][7] + bb[7];
        *(float4*)&C[rowoff + tn * 4] = o0;
        *(float4*)&C[rowoff + 64 + tn * 4] = o1;
    }
}

// fast tanh: 1 - 2/(exp2(2*log2e*x)+1); exact at +/-inf, ~1e-6 abs error
__device__ __forceinline__ float fast_tanh(float x)
{
    const float e = __builtin_amdgcn_exp2f(x * 2.88539008177793f);
    return fmaf(-2.0f, __builtin_amdgcn_rcpf(e + 1.0f), 1.0f);
}

// ---------------------------------------------------------------------------
// Recurrent scan. Persistent cooperative kernel, grid = 256 WGs x 512 thr.
// Group = batch element b (64 groups); 4 slice-WGs per group; slice s owns
// output rows [128s, 128s+128).
//
// W residency: the per-thread 128-float W row-chunk is stashed in 128 AGPRs
// via v_accvgpr_write_b32 (scalar "a"-constraint asm; values produced by
// volatile asm are NOT rematerializable, so the allocator must keep them
// register-resident -- unlike rounds 3-5 where plain loads were legally
// re-issued from L2 every step, making the scan L2-BW-bound).
// Per step: 128 volatile v_accvgpr_read + 128 fmac + 32 broadcast
// ds_read_b128 of h. Budget: 128 AGPR + ~65 VGPR < 256 (launch_bounds 512,2).
//
// Sync: tagged-u64 relaxed agent-scope atomics, parity double-buffered
// (proof rounds 2-5); own rows self-routed via LDS; ONE barrier per step.
// ---------------------------------------------------------------------------
#define AGDECL(i) float W##i##_0, W##i##_1, W##i##_2, W##i##_3
#define AGLOAD(i) do { float4 v = *(const float4*)&wsrc[(i) * 4]; \
    asm volatile("v_accvgpr_write_b32 %0, %1" : "=a"(W##i##_0) : "v"(v.x)); \
    asm volatile("v_accvgpr_write_b32 %0, %1" : "=a"(W##i##_1) : "v"(v.y)); \
    asm volatile("v_accvgpr_write_b32 %0, %1" : "=a"(W##i##_2) : "v"(v.z)); \
    asm volatile("v_accvgpr_write_b32 %0, %1" : "=a"(W##i##_3) : "v"(v.w)); } while (0)
#define AGFMA(i, acc) do { float4 hh = hq[i]; float t0, t1, t2, t3; \
    asm volatile("v_accvgpr_read_b32 %0, %1" : "=v"(t0) : "a"(W##i##_0)); \
    asm volatile("v_accvgpr_read_b32 %0, %1" : "=v"(t1) : "a"(W##i##_1)); \
    asm volatile("v_accvgpr_read_b32 %0, %1" : "=v"(t2) : "a"(W##i##_2)); \
    asm volatile("v_accvgpr_read_b32 %0, %1" : "=v"(t3) : "a"(W##i##_3)); \
    acc = fmaf(t0, hh.x, acc); acc = fmaf(t1, hh.y, acc); \
    acc = fmaf(t2, hh.z, acc); acc = fmaf(t3, hh.w, acc); } while (0)

__global__ __launch_bounds__(512, 2)
void rnn_scan(const float* __restrict__ proj, const float* __restrict__ Whh,
              const float* __restrict__ bhh, float* __restrict__ out,
              float* __restrict__ hidden, unsigned long long* __restrict__ hbuf)
{
    __shared__ float hS[2][528];   // [parity][512 + 4-float pad per 128]

    const int t   = threadIdx.x;
    const int bid = blockIdx.x;
    const int s   = bid >> 6;          // slice 0..3 (bid stride 64 -> same XCD)
    const int b   = bid & 63;          // batch element
    const int w   = t >> 6;            // wave 0..7
    const int l   = t & 63;
    const int lr  = l & 15;            // row-in-wave
    const int lc  = l >> 4;            // k-chunk 0..3
    const int row = s * 128 + w * 16 + lr;   // global output row

    // ---- one-time: W row-chunk -> 128 AGPRs ----
    const float* wsrc = &Whh[(size_t)row * HID + lc * 128];
    AGDECL(0);  AGDECL(1);  AGDECL(2);  AGDECL(3);
    AGDECL(4);  AGDECL(5);  AGDECL(6);  AGDECL(7);
    AGDECL(8);  AGDECL(9);  AGDECL(10); AGDECL(11);
    AGDECL(12); AGDECL(13); AGDECL(14); AGDECL(15);
    AGDECL(16); AGDECL(17); AGDECL(18); AGDECL(19);
    AGDECL(20); AGDECL(21); AGDECL(22); AGDECL(23);
    AGDECL(24); AGDECL(25); AGDECL(26); AGDECL(27);
    AGDECL(28); AGDECL(29); AGDECL(30); AGDECL(31);
    AGLOAD(0);  AGLOAD(1);  AGLOAD(2);  AGLOAD(3);
    AGLOAD(4);  AGLOAD(5);  AGLOAD(6);  AGLOAD(7);
    AGLOAD(8);  AGLOAD(9);  AGLOAD(10); AGLOAD(11);
    AGLOAD(12); AGLOAD(13); AGLOAD(14); AGLOAD(15);
    AGLOAD(16); AGLOAD(17); AGLOAD(18); AGLOAD(19);
    AGLOAD(20); AGLOAD(21); AGLOAD(22); AGLOAD(23);
    AGLOAD(24); AGLOAD(25); AGLOAD(26); AGLOAD(27);
    AGLOAD(28); AGLOAD(29); AGLOAD(30); AGLOAD(31);

    const float breg = bhh[row];

    // init both LDS parities to h=0 (also covers step-0 self-routed slots)
    for (int i = t; i < 528; i += 512) { hS[0][i] = 0.f; hS[1][i] = 0.f; }
    __syncthreads();

    const bool own   = (t >> 7) == s;          // own k-range (self-routed)
    const int  pad_t = t + ((t >> 7) << 2);    // padded LDS index for k = t

    // proj pipeline: value for step 0
    const bool pub = (lc == 0);
    float pv_next = 0.f;
    if (pub) pv_next = proj[(size_t)b * HID + row];

    for (int step = 0; step < SEQ; ++step) {
        const int p = step & 1;

        // ---- consume pipelined proj; issue load for step+1 ----
        const float pv = pv_next;
        if (pub && step + 1 < SEQ)
            pv_next = proj[((size_t)(step + 1) * BATCH + b) * HID + row];

        // ---- poll + stage non-own h (one tagged u64 per thread; whole
        //      waves are own/non-own, so no divergence) ----
        if (!own) {
            const unsigned long long* src =
                hbuf + (size_t)p * (BATCH * HID) + (size_t)b * HID + t;
            const unsigned int want = (unsigned int)step;
            unsigned long long x;
            int spins = 0;
            for (;;) {
                x = __hip_atomic_load(src, __ATOMIC_RELAXED, __HIP_MEMORY_SCOPE_AGENT);
                if ((unsigned int)(x >> 32) == want) break;
                __builtin_amdgcn_s_sleep(1);
                if (++spins > 4096) {              // hang-proofing only
                    __builtin_amdgcn_fence(__ATOMIC_ACQUIRE, "agent");
                    spins = 0;
                }
            }
            hS[p][pad_t] = __uint_as_float((unsigned int)x);
        }
        __syncthreads();   // the ONLY barrier per step

        // ---- matvec: W from AGPRs x broadcast LDS h ----
        const float4* hq = (const float4*)&hS[p][lc * 132];
        float a0 = 0.f, a1 = 0.f, a2 = 0.f, a3 = 0.f;
        AGFMA(0,  a0); AGFMA(1,  a1); AGFMA(2,  a2); AGFMA(3,  a3);
        AGFMA(4,  a0); AGFMA(5,  a1); AGFMA(6,  a2); AGFMA(7,  a3);
        AGFMA(8,  a0); AGFMA(9,  a1); AGFMA(10, a2); AGFMA(11, a3);
        AGFMA(12, a0); AGFMA(13, a1); AGFMA(14, a2); AGFMA(15, a3);
        AGFMA(16, a0); AGFMA(17, a1); AGFMA(18, a2); AGFMA(19, a3);
        AGFMA(20, a0); AGFMA(21, a1); AGFMA(22, a2); AGFMA(23, a3);
        AGFMA(24, a0); AGFMA(25, a1); AGFMA(26, a2); AGFMA(27, a3);
        AGFMA(28, a0); AGFMA(29, a1); AGFMA(30, a2); AGFMA(31, a3);
        float sum = (a0 + a1) + (a2 + a3);
        // reduce across the 4 lanes sharing a row (l, l+16, l+32, l+48)
        sum += __shfl_xor(sum, 16, 64);
        sum += __shfl_xor(sum, 32, 64);

        // ---- tanh + publish (lanes lc==0), self-route own rows via LDS ----
        if (pub) {
            const float hn = fast_tanh(pv + breg + sum);
            out[((size_t)step * BATCH + b) * HID + row] = hn;
            const unsigned long long pk =
                ((unsigned long long)(unsigned int)(step + 1) << 32) |
                (unsigned long long)__float_as_uint(hn);
            __hip_atomic_store(
                &hbuf[(size_t)(p ^ 1) * (BATCH * HID) + (size_t)b * HID + row],
                pk, __ATOMIC_RELAXED, __HIP_MEMORY_SCOPE_AGENT);
            hS[p ^ 1][row + ((row >> 7) << 2)] = hn;   // self-route (own rows)
            if (step == SEQ - 1) hidden[(size_t)b * HID + row] = hn;
        }
        // no trailing barrier: next step's pre-barrier LDS writes touch only
        // parity p^1 slots disjoint from this step's hS[p] reads, and each
        // thread's own reads precede its next-step writes in program order.
    }
}

// ---------------------------------------------------------------------------
extern "C" void kernel_launch(void* const* d_in, const int* in_sizes, int n_in,
                              void* d_out, int out_size, void* d_ws, size_t ws_size,
                              hipStream_t stream)
{
    (void)in_sizes; (void)n_in; (void)out_size; (void)ws_size;

    const float* x    = (const float*)d_in[0];
    const float* Wih0 = (const float*)d_in[1];
    const float* Whh0 = (const float*)d_in[2];
    const float* bih0 = (const float*)d_in[3];
    const float* bhh0 = (const float*)d_in[4];
    const float* Wih1 = (const float*)d_in[5];
    const float* Whh1 = (const float*)d_in[6];
    const float* bih1 = (const float*)d_in[7];
    const float* bhh1 = (const float*)d_in[8];

    float* out1   = (float*)d_out;                        // [S][B][H]
    float* hidden = out1 + (size_t)SEQ * BATCH * HID;     // [2][B][H]

    float* proj = (float*)d_ws;                           // [S][B][H] f32
    unsigned long long* hbufA =
        (unsigned long long*)(proj + (size_t)SEQ * BATCH * HID);  // [2][B][H] u64
    unsigned long long* hbufB = hbufA + (size_t)2 * BATCH * HID;  // [2][B][H] u64

    // zero both layers' tagged h-state buffers (tag 0 == epoch 0, h = 0)
    hipMemsetAsync(hbufA, 0, (size_t)4 * BATCH * HID * sizeof(unsigned long long),
                   stream);

    // ---- layer 0 ----
    proj_gemm<<<dim3(4096), dim3(256), 0, stream>>>(x, Wih0, bih0, proj);
    {
        const float* p = proj; const float* w = Whh0; const float* bb = bhh0;
        float* o = out1; float* hd = hidden; unsigned long long* hb = hbufA;
        void* args[] = {&p, &w, &bb, &o, &hd, &hb};
        hipLaunchCooperativeKernel((const void*)rnn_scan, dim3(256), dim3(512),
                                   args, 0, stream);
    }

    // ---- layer 1 (out0 staged in d_out's out1 region) ----
    proj_gemm<<<dim3(4096), dim3(256), 0, stream>>>(out1, Wih1, bih1, proj);
    {
        const float* p = proj; const float* w = Whh1; const float* bb = bhh1;
        float* o = out1; float* hd = hidden + BATCH * HID; unsigned long long* hb = hbufB;
        void* args[] = {&p, &w, &bb, &o, &hd, &hb};
        hipLaunchCooperativeKernel((const void*)rnn_scan, dim3(256), dim3(512),
                                   args, 0, stream);
    }
}